// Round 10
// baseline (319.219 us; speedup 1.0000x reference)
//
#include <hip/hip_runtime.h>
#include <math.h>

#define EPSF 1e-8f
#define Tn 512
#define Dn 64
#define NBLK 256
#define NTHR 512

__device__ __forceinline__ float sigmoidf_(float x){ return 1.0f/(1.0f+expf(-x)); }
__device__ __forceinline__ float softplusf_(float x){ return fmaxf(x,0.0f) + log1pf(expf(-fabsf(x))); }

__device__ __forceinline__ float wrs(float v){
  #pragma unroll
  for (int off=1; off<64; off<<=1) v += __shfl_xor(v, off, 64);
  return v;
}
__device__ __forceinline__ float wrm(float v){
  #pragma unroll
  for (int off=1; off<64; off<<=1) v = fmaxf(v, __shfl_xor(v, off, 64));
  return v;
}

struct __align__(16) Smem {
  union { float part[16*512]; float pvp[32*4*64]; } u;  // 32 KB
  float P[512*4];        // 8 KB
  float s_i[64*4];       // [k][i]
  float redw[2][8][4];
  float comb[4][128];
  float gred[64*5];
  float tl[4];
  float pl[128];
  float h1[64];
  float hb[128];
  float combb[128];
  float cbl[64];
};

// Grid barrier: RELEASE on the add (one L2 writeback), RELAXED polls (no cache
// invalidation per poll — R5's bug), ONE ACQUIRE load once target is reached.
__device__ __forceinline__ void gbar(unsigned* cnt, unsigned target){
  __syncthreads();
  if (threadIdx.x == 0){
    __hip_atomic_fetch_add(cnt, 1u, __ATOMIC_RELEASE, __HIP_MEMORY_SCOPE_AGENT);
    while (__hip_atomic_load(cnt, __ATOMIC_RELAXED, __HIP_MEMORY_SCOPE_AGENT) < target)
      __builtin_amdgcn_s_sleep(1);
    (void)__hip_atomic_load(cnt, __ATOMIC_ACQUIRE, __HIP_MEMORY_SCOPE_AGENT);
  }
  __syncthreads();
}

// pnorm for own row (wave i_ = row, lanes = d); s kept in LDS for next dot + k-major global
__device__ __forceinline__ void pnorm_ps(Smem& sm, float xg, int b, int r, int i_, int d_,
                                         float* __restrict__ sT_out){
  float s = softplusf_(xg);
  float sum = wrs(s);
  float p = fmaxf(s/(sum+EPSF), EPSF);
  float s2 = wrs(p);
  float sq = sqrtf(p/(s2+EPSF));
  sm.s_i[d_*4+i_] = sq;
  sT_out[(size_t)b*Dn*Tn + (size_t)d_*Tn + r] = sq;
}

// gate dot: 8 threads per output d, each dots 16 of 128; 4 rows
__device__ __forceinline__ void gate_dot(Smem& sm, const float* __restrict__ Wfb, int tid, int lane){
  int dd = tid >> 3, k8 = tid & 7;
  const float4* wp = (const float4*)(Wfb + (size_t)dd*128 + k8*16);
  float4 w0 = wp[0], w1 = wp[1], w2 = wp[2], w3 = wp[3];
  float ga[4];
  #pragma unroll
  for (int i=0;i<4;i++){
    float4 c0 = *(const float4*)&sm.comb[i][k8*16];
    float4 c1 = *(const float4*)&sm.comb[i][k8*16+4];
    float4 c2 = *(const float4*)&sm.comb[i][k8*16+8];
    float4 c3 = *(const float4*)&sm.comb[i][k8*16+12];
    ga[i] = w0.x*c0.x + w0.y*c0.y + w0.z*c0.z + w0.w*c0.w
          + w1.x*c1.x + w1.y*c1.y + w1.z*c1.z + w1.w*c1.w
          + w2.x*c2.x + w2.y*c2.y + w2.z*c2.z + w2.w*c2.w
          + w3.x*c3.x + w3.y*c3.y + w3.z*c3.z + w3.w*c3.w;
  }
  #pragma unroll
  for (int off=1; off<8; off<<=1){
    ga[0]+=__shfl_xor(ga[0],off,64); ga[1]+=__shfl_xor(ga[1],off,64);
    ga[2]+=__shfl_xor(ga[2],off,64); ga[3]+=__shfl_xor(ga[3],off,64);
  }
  if ((lane&7)==0){
    sm.gred[dd*5+0]=ga[0]; sm.gred[dd*5+1]=ga[1];
    sm.gred[dd*5+2]=ga[2]; sm.gred[dd*5+3]=ga[3];
  }
}

// MODE 0: write x + pnorm ; 1: write x + stash o (pre-basin)
// MODE 2: fbgate(next) + write x + pnorm ; 3: final residual -> xout(=out)
template<int MODE>
__device__ __forceinline__ void attn_phase(Smem& sm, int tid, int wav, int lane,
    int b, int row0, int r0, int l, float& xreg, float prevreg,
    const float* __restrict__ xin, const float* __restrict__ sT,
    float* __restrict__ xout, float* __restrict__ sT_out,
    const float* __restrict__ res_scale,
    const float* __restrict__ Wfb, const float* __restrict__ bfb,
    const float* __restrict__ basin_seq, const float* __restrict__ rsg){
  int i_ = tid>>6, d_ = lane;
  float invT = 1.0f/fmaxf(sm.tl[l], 1e-6f);
  // ---- dot: thread (g, kq); g covers 4 j via float4, kq a 16-k slice
  {
    int g = tid & 127, kq = tid >> 7;
    const float4* sT4 = (const float4*)(sT + (size_t)b*Dn*Tn);
    float4 a0={0,0,0,0},a1=a0,a2=a0,a3=a0;
    int kb = kq*16;
    #pragma unroll
    for (int kk=0;kk<16;kk++){
      int k = kb+kk;
      float4 v = sT4[(size_t)k*128 + g];
      float4 si = *(const float4*)&sm.s_i[k*4];
      a0.x=fmaf(si.x,v.x,a0.x); a0.y=fmaf(si.x,v.y,a0.y); a0.z=fmaf(si.x,v.z,a0.z); a0.w=fmaf(si.x,v.w,a0.w);
      a1.x=fmaf(si.y,v.x,a1.x); a1.y=fmaf(si.y,v.y,a1.y); a1.z=fmaf(si.y,v.z,a1.z); a1.w=fmaf(si.y,v.w,a1.w);
      a2.x=fmaf(si.z,v.x,a2.x); a2.y=fmaf(si.z,v.y,a2.y); a2.z=fmaf(si.z,v.z,a2.z); a2.w=fmaf(si.z,v.w,a2.w);
      a3.x=fmaf(si.w,v.x,a3.x); a3.y=fmaf(si.w,v.y,a3.y); a3.z=fmaf(si.w,v.z,a3.z); a3.w=fmaf(si.w,v.w,a3.w);
    }
    *(float4*)&sm.u.part[(0*4+kq)*512 + g*4] = a0;
    *(float4*)&sm.u.part[(1*4+kq)*512 + g*4] = a1;
    *(float4*)&sm.u.part[(2*4+kq)*512 + g*4] = a2;
    *(float4*)&sm.u.part[(3*4+kq)*512 + g*4] = a3;
  }
  __syncthreads();
  // ---- combine + softmax (thread j = tid)
  {
    int j = tid;
    float lg[4];
    #pragma unroll
    for (int i=0;i<4;i++){
      float a = sm.u.part[(i*4+0)*512+j]+sm.u.part[(i*4+1)*512+j]
              + sm.u.part[(i*4+2)*512+j]+sm.u.part[(i*4+3)*512+j];
      lg[i] = -2.0f*acosf(fminf(fmaxf(a,-1.0f+1e-6f),1.0f-1e-6f))*invT;
    }
    float m0=wrm(lg[0]),m1=wrm(lg[1]),m2=wrm(lg[2]),m3=wrm(lg[3]);
    if (lane==0){ sm.redw[0][wav][0]=m0; sm.redw[0][wav][1]=m1; sm.redw[0][wav][2]=m2; sm.redw[0][wav][3]=m3; }
    __syncthreads();
    float mv0=sm.redw[0][0][0],mv1=sm.redw[0][0][1],mv2=sm.redw[0][0][2],mv3=sm.redw[0][0][3];
    #pragma unroll
    for (int w=1;w<8;w++){
      mv0=fmaxf(mv0,sm.redw[0][w][0]); mv1=fmaxf(mv1,sm.redw[0][w][1]);
      mv2=fmaxf(mv2,sm.redw[0][w][2]); mv3=fmaxf(mv3,sm.redw[0][w][3]);
    }
    float4 ev = {expf(lg[0]-mv0),expf(lg[1]-mv1),expf(lg[2]-mv2),expf(lg[3]-mv3)};
    *(float4*)&sm.P[j*4] = ev;
    float q0=wrs(ev.x),q1=wrs(ev.y),q2=wrs(ev.z),q3=wrs(ev.w);
    if (lane==0){ sm.redw[1][wav][0]=q0; sm.redw[1][wav][1]=q1; sm.redw[1][wav][2]=q2; sm.redw[1][wav][3]=q3; }
  }
  __syncthreads();
  // ---- PV: thread (jg, dq); 16 j's, float4 along d
  {
    int jg = tid>>4, dq = tid&15;
    const float4* x4 = (const float4*)(xin + (size_t)b*Tn*Dn);
    float4 o0={0,0,0,0},o1=o0,o2=o0,o3=o0;
    int jb = jg*16;
    #pragma unroll
    for (int jj=0;jj<16;jj++){
      int j = jb+jj;
      float4 xv = x4[(size_t)j*16 + dq];
      float4 pw = *(const float4*)&sm.P[j*4];
      o0.x=fmaf(pw.x,xv.x,o0.x); o0.y=fmaf(pw.x,xv.y,o0.y); o0.z=fmaf(pw.x,xv.z,o0.z); o0.w=fmaf(pw.x,xv.w,o0.w);
      o1.x=fmaf(pw.y,xv.x,o1.x); o1.y=fmaf(pw.y,xv.y,o1.y); o1.z=fmaf(pw.y,xv.z,o1.z); o1.w=fmaf(pw.y,xv.w,o1.w);
      o2.x=fmaf(pw.z,xv.x,o2.x); o2.y=fmaf(pw.z,xv.y,o2.y); o2.z=fmaf(pw.z,xv.z,o2.z); o2.w=fmaf(pw.z,xv.w,o2.w);
      o3.x=fmaf(pw.w,xv.x,o3.x); o3.y=fmaf(pw.w,xv.y,o3.y); o3.z=fmaf(pw.w,xv.z,o3.z); o3.w=fmaf(pw.w,xv.w,o3.w);
    }
    *(float4*)&sm.u.pvp[(jg*4+0)*64 + dq*4] = o0;
    *(float4*)&sm.u.pvp[(jg*4+1)*64 + dq*4] = o1;
    *(float4*)&sm.u.pvp[(jg*4+2)*64 + dq*4] = o2;
    *(float4*)&sm.u.pvp[(jg*4+3)*64 + dq*4] = o3;
  }
  __syncthreads();
  // ---- epilogue (tid<256: wave = row)
  float o = 0.f;
  if (tid < 256){
    float ss = 0.f;
    #pragma unroll
    for (int jg2=0;jg2<32;jg2++) ss += sm.u.pvp[(jg2*4+i_)*64+d_];
    float sv = 0.f;
    #pragma unroll
    for (int w=0;w<8;w++) sv += sm.redw[1][w][i_];
    float attn = ss/sv;
    o = xreg + res_scale[l]*(attn - xreg);
  }
  if constexpr (MODE==0){
    if (tid<256){
      xout[(size_t)(row0+i_)*Dn+d_] = o;
      xreg = o;
      pnorm_ps(sm, o, b, r0+i_, i_, d_, sT_out);
    }
  } else if constexpr (MODE==1){
    if (tid<256){
      xout[(size_t)(row0+i_)*Dn+d_] = o;
      xreg = o;
      sm.comb[i_][d_] = o;
    }
  } else if constexpr (MODE==2){
    if (tid<256){ sm.comb[i_][d_]=o; sm.comb[i_][64+d_]=prevreg; }
    __syncthreads();
    gate_dot(sm, Wfb, tid, lane);
    __syncthreads();
    if (tid<256){
      float g = sigmoidf_(sm.gred[d_*5+i_] + bfb[d_]);
      float xg = o*g + prevreg*(1.0f-g);
      xout[(size_t)(row0+i_)*Dn+d_] = xg;
      xreg = xg;
      pnorm_ps(sm, xg, b, r0+i_, i_, d_, sT_out);
    }
  } else {
    if (tid<256){
      float c = 0.01f*rsg[0];
      xout[(size_t)(row0+i_)*Dn+d_] = o + c*(o - basin_seq[(size_t)(row0+i_)*Dn+d_]);
    }
  }
  __syncthreads();
}

__global__ __launch_bounds__(NTHR) void k_persist(
    const float* __restrict__ basin_seq, const float* __restrict__ basin_coords,
    const float* __restrict__ W_temp, const float* __restrict__ b_temp,
    const float* __restrict__ res_scale, const float* __restrict__ W_fb,
    const float* __restrict__ b_fb, const float* __restrict__ Wc1,
    const float* __restrict__ bc1, const float* __restrict__ Wc2,
    const float* __restrict__ bc2, const float* __restrict__ Wu,
    const float* __restrict__ bu, const float* __restrict__ rsg,
    float* __restrict__ out, unsigned* __restrict__ cnt, float* __restrict__ pooled_g,
    float* __restrict__ sTA, float* __restrict__ sTB,
    float* __restrict__ xA, float* __restrict__ xB){
  __shared__ Smem sm;
  int tid = threadIdx.x, wav = tid>>6, lane = tid&63;
  int row0 = blockIdx.x*4, b = row0>>9, r0 = row0&511;
  int i_ = tid>>6, d_ = lane;
  unsigned tgt = 0;
  float xreg=0.f, st0r=0.f, st1r=0.f, st2r=0.f, st3r=0.f;

  // ---- init: temps(pass0) redundant per block + pnorm(basin_seq) own rows
  if (tid < 256){
    float v = wrs(W_temp[i_*Dn + lane] * basin_coords[lane]);
    if (lane==0) sm.tl[i_] = sigmoidf_(v + b_temp[i_]) + 0.5f;
  }
  if (tid < 256){
    xreg = basin_seq[(size_t)(row0+i_)*Dn + d_];
    pnorm_ps(sm, xreg, b, r0+i_, i_, d_, sTA);
  }
  gbar(cnt, tgt += NBLK);

  // ---- pass 0
  attn_phase<0>(sm,tid,wav,lane,b,row0,r0, 0, xreg, 0.f, basin_seq, sTA, xA, sTB,
                res_scale, nullptr,nullptr,nullptr,nullptr);
  st0r = xreg;
  gbar(cnt, tgt += NBLK);
  attn_phase<0>(sm,tid,wav,lane,b,row0,r0, 1, xreg, 0.f, xA, sTB, xB, sTA,
                res_scale, nullptr,nullptr,nullptr,nullptr);
  st1r = xreg;
  gbar(cnt, tgt += NBLK);
  attn_phase<0>(sm,tid,wav,lane,b,row0,r0, 2, xreg, 0.f, xB, sTA, xA, sTB,
                res_scale, nullptr,nullptr,nullptr,nullptr);
  st2r = xreg;
  gbar(cnt, tgt += NBLK);
  attn_phase<1>(sm,tid,wav,lane,b,row0,r0, 3, xreg, 0.f, xA, sTB, xB, nullptr,
                res_scale, nullptr,nullptr,nullptr,nullptr);
  st3r = xreg;
  // pooled partial (own 4 rows) -> global atomic
  if (tid < 64){
    float part = sm.comb[0][tid]+sm.comb[1][tid]+sm.comb[2][tid]+sm.comb[3][tid];
    atomicAdd(&pooled_g[b*64+tid], part);
  }
  gbar(cnt, tgt += NBLK);

  // ---- basin update (redundant per block) + temps(pass1)
  if (tid < 128)
    sm.pl[tid] = __hip_atomic_load(&pooled_g[tid], __ATOMIC_RELAXED, __HIP_MEMORY_SCOPE_AGENT) * (1.0f/512.0f);
  __syncthreads();
  if (tid < 64){
    int bb=tid>>5, h=tid&31;
    float acc=0.f;
    #pragma unroll 8
    for (int d2=0; d2<64; d2++) acc += sm.pl[bb*64+d2]*Wc1[h*64+d2];
    sm.h1[tid] = tanhf(acc + bc1[h]);
  }
  __syncthreads();
  if (tid < 128){
    int bb=tid>>6, dd=tid&63;
    float acc=0.f;
    #pragma unroll 8
    for (int h2=0; h2<32; h2++) acc += sm.h1[bb*32+h2]*Wc2[dd*32+h2];
    sm.hb[tid] = tanhf(acc + bc2[dd]);
  }
  __syncthreads();
  if (tid < 64){
    float agg = 0.5f*(sm.hb[tid] + sm.hb[64+tid]);
    sm.combb[tid] = basin_coords[tid];
    sm.combb[64+tid] = agg;
  }
  __syncthreads();
  if (tid < 64){
    float acc=0.f;
    #pragma unroll 8
    for (int k=0;k<128;k++) acc += Wu[tid*128+k]*sm.combb[k];
    float g = sigmoidf_(acc + bu[tid]);
    sm.cbl[tid] = sm.combb[tid]*(1.0f-g) + sm.combb[64+tid]*g;
  }
  __syncthreads();
  if (tid < 256){
    float v = wrs(W_temp[i_*Dn + lane] * sm.cbl[lane]);
    if (lane==0) sm.tl[i_] = sigmoidf_(v + b_temp[i_]) + 0.5f;
  }
  // ---- pass-1 layer-0 fbgate on own rows: x = st3r(reg), prev = st0r(reg)
  if (tid < 256){ sm.comb[i_][d_] = xreg; sm.comb[i_][64+d_] = st0r; }
  __syncthreads();
  gate_dot(sm, W_fb, tid, lane);
  __syncthreads();
  if (tid < 256){
    float g = sigmoidf_(sm.gred[d_*5+i_] + b_fb[d_]);
    float xg = xreg*g + st0r*(1.0f-g);
    xreg = xg;
    xA[(size_t)(row0+i_)*Dn + d_] = xg;
    pnorm_ps(sm, xg, b, r0+i_, i_, d_, sTA);
  }
  gbar(cnt, tgt += NBLK);

  // ---- pass 1
  attn_phase<2>(sm,tid,wav,lane,b,row0,r0, 0, xreg, st1r, xA, sTA, xB, sTB,
                res_scale, W_fb + (size_t)1*Dn*2*Dn, b_fb + 1*Dn, nullptr,nullptr);
  gbar(cnt, tgt += NBLK);
  attn_phase<2>(sm,tid,wav,lane,b,row0,r0, 1, xreg, st2r, xB, sTB, xA, sTA,
                res_scale, W_fb + (size_t)2*Dn*2*Dn, b_fb + 2*Dn, nullptr,nullptr);
  gbar(cnt, tgt += NBLK);
  attn_phase<2>(sm,tid,wav,lane,b,row0,r0, 2, xreg, st3r, xA, sTA, xB, sTB,
                res_scale, W_fb + (size_t)3*Dn*2*Dn, b_fb + 3*Dn, nullptr,nullptr);
  gbar(cnt, tgt += NBLK);
  attn_phase<3>(sm,tid,wav,lane,b,row0,r0, 3, xreg, 0.f, xB, sTB, out, nullptr,
                res_scale, nullptr,nullptr, basin_seq, rsg);
}

extern "C" void kernel_launch(void* const* d_in, const int* in_sizes, int n_in,
                              void* d_out, int out_size, void* d_ws, size_t ws_size,
                              hipStream_t stream) {
  const float* basin_seq    = (const float*)d_in[0];
  const float* basin_coords = (const float*)d_in[1];
  const float* W_temp       = (const float*)d_in[2];
  const float* b_temp       = (const float*)d_in[3];
  const float* res_scale    = (const float*)d_in[4];
  const float* W_fb         = (const float*)d_in[5];
  const float* b_fb         = (const float*)d_in[6];
  const float* Wc1          = (const float*)d_in[7];
  const float* bc1          = (const float*)d_in[8];
  const float* Wc2          = (const float*)d_in[9];
  const float* bc2          = (const float*)d_in[10];
  const float* Wu           = (const float*)d_in[11];
  const float* bu           = (const float*)d_in[12];
  const float* rsg          = (const float*)d_in[13];
  float* out = (float*)d_out;
  float* ws  = (float*)d_ws;

  unsigned* cnt   = (unsigned*)d_ws;
  float* pooled_g = ws + 16;
  float* base     = ws + 256;
  const size_t N  = (size_t)Tn*2*Dn; // 65536
  float* sTA = base;
  float* sTB = base + N;
  float* xA  = base + 2*N;
  float* xB  = base + 3*N;

  (void)hipMemsetAsync(d_ws, 0, 1024, stream);   // zero barrier counter + pooled accumulator
  k_persist<<<NBLK, NTHR, 0, stream>>>(basin_seq, basin_coords, W_temp, b_temp,
                                       res_scale, W_fb, b_fb, Wc1, bc1, Wc2, bc2,
                                       Wu, bu, rsg, out, cnt, pooled_g,
                                       sTA, sTB, xA, xB);
}

// Round 11
// 177.042 us; speedup vs baseline: 1.8031x; 1.8031x over previous
//
#include <hip/hip_runtime.h>
#include <math.h>

#define EPSF 1e-8f
#define Tn 512
#define Dn 64
#define ROWS 1024
#define NELEM 65536

typedef _Float16 half_t;
typedef __attribute__((ext_vector_type(4))) _Float16 half4;

__device__ __forceinline__ float sigmoidf_(float x){ return 1.0f/(1.0f+expf(-x)); }
__device__ __forceinline__ float softplusf_(float x){ return fmaxf(x,0.0f) + log1pf(expf(-fabsf(x))); }

__device__ __forceinline__ float wrs(float v){
  #pragma unroll
  for (int off=1; off<64; off<<=1) v += __shfl_xor(v, off, 64);
  return v;
}
__device__ __forceinline__ float wrm(float v){
  #pragma unroll
  for (int off=1; off<64; off<<=1) v = fmaxf(v, __shfl_xor(v, off, 64));
  return v;
}

// pnorm for one row (one full wave per row): fp32 row-major sbuf + fp16 k-major sTh
__device__ __forceinline__ void pnorm_w(float xg, int b, int r, int row, int d,
                                        float* __restrict__ sbuf_out,
                                        half_t* __restrict__ sTh_out){
  float s = softplusf_(xg);
  float sum = wrs(s);
  float p = fmaxf(s/(sum+EPSF), EPSF);
  float s2 = wrs(p);
  float sq = sqrtf(p/(s2+EPSF));
  sbuf_out[(size_t)row*Dn + d] = sq;
  sTh_out[(size_t)b*Dn*Tn + (size_t)d*Tn + r] = (half_t)sq;
}

// ---- prologue: pnorm(basin_seq) + fp16 copy (blocks 0..255) ; temps (block 256)
__global__ __launch_bounds__(256) void k_prologue(
    const float* __restrict__ basin_seq, float* __restrict__ sA, half_t* __restrict__ sThA,
    half_t* __restrict__ xhBS,
    const float* __restrict__ W_temp, const float* __restrict__ b_temp,
    const float* __restrict__ cb0, float* __restrict__ temps){
  int tid = threadIdx.x, wid = tid>>6, lane = tid&63;
  if (blockIdx.x < 256){
    int row = blockIdx.x*4 + wid;
    float xv = basin_seq[(size_t)row*Dn+lane];
    xhBS[(size_t)row*Dn+lane] = (half_t)xv;
    pnorm_w(xv, row>>9, row&511, row, lane, sA, sThA);
  } else if (tid < 64){
    float cbv = cb0[tid];
    #pragma unroll
    for (int l=0;l<4;l++){
      float v = wrs(W_temp[l*Dn + tid]*cbv);
      if (tid==0) temps[l] = sigmoidf_(v + b_temp[l]) + 0.5f;
    }
  }
}

// gate dot (NI=2): 8 threads per output d, each dots 16 of 128
__device__ __forceinline__ void gate_dot2(float (*comb)[128], float* gred,
                                          const float* __restrict__ Wfb, int tid, int lane){
  int dd = tid >> 3, k8 = tid & 7;
  const float4* wp = (const float4*)(Wfb + (size_t)dd*128 + k8*16);
  float4 w0 = wp[0], w1 = wp[1], w2 = wp[2], w3 = wp[3];
  float ga[2];
  #pragma unroll
  for (int i=0;i<2;i++){
    float4 c0 = *(const float4*)&comb[i][k8*16];
    float4 c1 = *(const float4*)&comb[i][k8*16+4];
    float4 c2 = *(const float4*)&comb[i][k8*16+8];
    float4 c3 = *(const float4*)&comb[i][k8*16+12];
    ga[i] = w0.x*c0.x + w0.y*c0.y + w0.z*c0.z + w0.w*c0.w
          + w1.x*c1.x + w1.y*c1.y + w1.z*c1.z + w1.w*c1.w
          + w2.x*c2.x + w2.y*c2.y + w2.z*c2.z + w2.w*c2.w
          + w3.x*c3.x + w3.y*c3.y + w3.z*c3.z + w3.w*c3.w;
  }
  #pragma unroll
  for (int off=1; off<8; off<<=1){
    ga[0] += __shfl_xor(ga[0],off,64); ga[1] += __shfl_xor(ga[1],off,64);
  }
  if ((lane&7)==0){ gred[dd*3+0]=ga[0]; gred[dd*3+1]=ga[1]; }
}

// ---- QFI attention, NI=2 rows/block, 512 threads, grid 512; fp16 streaming operands.
// MODE 0: write x(+fp16) + pnorm ; 1: write x only (pre-basin)
// MODE 2: fbgate(next layer) + write x(+fp16) + pnorm ; 3: final residual -> out
template<int MODE>
__global__ __launch_bounds__(512) void k_attn(
    const float* __restrict__ xin, const half_t* __restrict__ xh,
    const float* __restrict__ sbuf, const half_t* __restrict__ sTh,
    const float* __restrict__ temps, const float* __restrict__ res_scale, int l,
    float* __restrict__ xout, half_t* __restrict__ xh_out,
    float* __restrict__ sbuf_out, half_t* __restrict__ sTh_out,
    const float* __restrict__ Wfb, const float* __restrict__ bfb,
    const float* __restrict__ prev,
    const float* __restrict__ basin_seq, const float* __restrict__ rsg){
  __shared__ __align__(16) union {
    float part[8*512];     // dot partials [(i*4+kq)][j]
    float pvp[32*2*64];    // PV partials [(jg*2+i)][d]
  } u;                     // 16 KB
  __shared__ __align__(8) float P[512*2];     // [j][i] exp weights
  __shared__ __align__(8) float s_i[64*2];    // [k][i]
  __shared__ float redw[2][8][2];
  __shared__ __align__(16) float comb[2][128];
  __shared__ float gred[64*3];

  int tid = threadIdx.x, wav = tid>>6, lane = tid&63;
  int row0 = blockIdx.x*2, b = row0>>9, r0 = row0&511;
  int i_ = tid>>6, d_ = lane;   // epilogue mapping for tid<128

  float xi_pre = 0.f, prev_pre = 0.f;
  if (tid < 128){
    s_i[d_*2 + i_] = sbuf[(size_t)(row0+i_)*Dn + d_];
    xi_pre = xin[(size_t)(row0+i_)*Dn + d_];
    if constexpr (MODE == 2) prev_pre = prev[(size_t)(row0+i_)*Dn + d_];
  }
  __syncthreads();

  float invT = 1.0f/fmaxf(temps[l], 1e-6f);
  // ---- dot phase: thread (g, kq); g covers 4 j's via half4, kq a 16-k slice
  {
    int g = tid & 127, kq = tid >> 7;
    const half4* sT4 = (const half4*)(sTh + (size_t)b*Dn*Tn);  // [k][128 half4]
    float4 a0 = {0,0,0,0}, a1 = a0;
    int kb = kq*16;
    #pragma unroll
    for (int kk=0; kk<16; ++kk){
      int k = kb + kk;
      half4 vh = sT4[(size_t)k*128 + g];
      float vx=(float)vh.x, vy=(float)vh.y, vz=(float)vh.z, vw=(float)vh.w;
      float2 si = *(const float2*)&s_i[k*2];
      a0.x=fmaf(si.x,vx,a0.x); a0.y=fmaf(si.x,vy,a0.y);
      a0.z=fmaf(si.x,vz,a0.z); a0.w=fmaf(si.x,vw,a0.w);
      a1.x=fmaf(si.y,vx,a1.x); a1.y=fmaf(si.y,vy,a1.y);
      a1.z=fmaf(si.y,vz,a1.z); a1.w=fmaf(si.y,vw,a1.w);
    }
    *(float4*)&u.part[(0*4+kq)*512 + g*4] = a0;
    *(float4*)&u.part[(1*4+kq)*512 + g*4] = a1;
  }
  __syncthreads();
  // ---- combine + logits + softmax (thread j = tid)
  {
    int j = tid;
    float a0 = u.part[0*512+j] + u.part[1*512+j] + u.part[2*512+j] + u.part[3*512+j];
    float a1 = u.part[4*512+j] + u.part[5*512+j] + u.part[6*512+j] + u.part[7*512+j];
    float l0 = -2.0f*acosf(fminf(fmaxf(a0,-1.0f+1e-6f),1.0f-1e-6f))*invT;
    float l1 = -2.0f*acosf(fminf(fmaxf(a1,-1.0f+1e-6f),1.0f-1e-6f))*invT;
    float m0=wrm(l0), m1=wrm(l1);
    if (lane==0){ redw[0][wav][0]=m0; redw[0][wav][1]=m1; }
    __syncthreads();
    float mv0=redw[0][0][0], mv1=redw[0][0][1];
    #pragma unroll
    for (int w=1;w<8;w++){ mv0=fmaxf(mv0,redw[0][w][0]); mv1=fmaxf(mv1,redw[0][w][1]); }
    float e0=expf(l0-mv0), e1=expf(l1-mv1);
    float2 ev = {e0,e1};
    *(float2*)&P[j*2] = ev;
    float q0=wrs(e0), q1=wrs(e1);
    if (lane==0){ redw[1][wav][0]=q0; redw[1][wav][1]=q1; }
  }
  __syncthreads();
  // ---- PV phase: thread (jg, dq); 16 j's, half4 along d
  {
    int jg = tid>>4, dq = tid&15;
    const half4* x4 = (const half4*)(xh + (size_t)b*Tn*Dn);  // [j][16 half4]
    float4 o0={0,0,0,0}, o1=o0;
    int jb = jg*16;
    #pragma unroll
    for (int jj=0; jj<16; ++jj){
      int j = jb + jj;
      half4 xvh = x4[(size_t)j*16 + dq];
      float xx=(float)xvh.x, xy=(float)xvh.y, xz=(float)xvh.z, xw=(float)xvh.w;
      float2 pw = *(const float2*)&P[j*2];
      o0.x=fmaf(pw.x,xx,o0.x); o0.y=fmaf(pw.x,xy,o0.y);
      o0.z=fmaf(pw.x,xz,o0.z); o0.w=fmaf(pw.x,xw,o0.w);
      o1.x=fmaf(pw.y,xx,o1.x); o1.y=fmaf(pw.y,xy,o1.y);
      o1.z=fmaf(pw.y,xz,o1.z); o1.w=fmaf(pw.y,xw,o1.w);
    }
    *(float4*)&u.pvp[(jg*2+0)*64 + dq*4] = o0;
    *(float4*)&u.pvp[(jg*2+1)*64 + dq*4] = o1;
  }
  __syncthreads();
  // ---- epilogue (tid<128: wave 0 = row 0, wave 1 = row 1)
  float o = 0.f;
  if (tid < 128){
    float ss = 0.f;
    #pragma unroll
    for (int jg=0; jg<32; ++jg) ss += u.pvp[(jg*2+i_)*64+d_];
    float sv = 0.f;
    #pragma unroll
    for (int w=0;w<8;w++) sv += redw[1][w][i_];
    float attn = ss/sv;
    o = xi_pre + res_scale[l]*(attn - xi_pre);
  }
  if constexpr (MODE == 0){
    if (tid < 128){
      xout[(size_t)(row0+i_)*Dn + d_] = o;
      xh_out[(size_t)(row0+i_)*Dn + d_] = (half_t)o;
      pnorm_w(o, b, r0+i_, row0+i_, d_, sbuf_out, sTh_out);
    }
  } else if constexpr (MODE == 1){
    if (tid < 128) xout[(size_t)(row0+i_)*Dn + d_] = o;
  } else if constexpr (MODE == 2){
    if (tid < 128){
      comb[i_][d_] = o;
      comb[i_][64+d_] = prev_pre;
    }
    __syncthreads();
    gate_dot2(comb, gred, Wfb, tid, lane);
    __syncthreads();
    if (tid < 128){
      float g = sigmoidf_(gred[d_*3+i_] + bfb[d_]);
      float xg = o*g + prev_pre*(1.0f-g);
      xout[(size_t)(row0+i_)*Dn + d_] = xg;
      xh_out[(size_t)(row0+i_)*Dn + d_] = (half_t)xg;
      pnorm_w(xg, b, r0+i_, row0+i_, d_, sbuf_out, sTh_out);
    }
  } else {
    if (tid < 128){
      float c = 0.01f * rsg[0];
      xout[(size_t)(row0+i_)*Dn + d_] = o + c*(o - basin_seq[(size_t)(row0+i_)*Dn + d_]);
    }
  }
}

// ---- blocks 0..255: pass-1 layer-0 fbgate + pnorm (4 rows); block 256: basin+temps
__global__ __launch_bounds__(256) void k_basinprep(
    const float* __restrict__ st3, const float* __restrict__ st0,
    const float* __restrict__ W_fb, const float* __restrict__ b_fb,
    float* __restrict__ xA, half_t* __restrict__ xhA,
    float* __restrict__ sA, half_t* __restrict__ sThA,
    const float* __restrict__ Wc1, const float* __restrict__ bc1,
    const float* __restrict__ Wc2, const float* __restrict__ bc2,
    const float* __restrict__ Wu,  const float* __restrict__ bu,
    const float* __restrict__ cb_in, float* __restrict__ cb_out,
    const float* __restrict__ W_temp, const float* __restrict__ b_temp,
    float* __restrict__ temps){
  int tid = threadIdx.x, wid = tid>>6, lane = tid&63;
  __shared__ __align__(16) float comb4[4][128];
  __shared__ float pooled[128];
  __shared__ float h1[64];
  __shared__ float hb[128];
  __shared__ float combb[128];
  if (blockIdx.x < 256){
    int row = blockIdx.x*4 + wid;
    float xv = st3[(size_t)row*Dn+lane];
    float pvv = st0[(size_t)row*Dn+lane];
    comb4[wid][lane] = xv; comb4[wid][64+lane] = pvv;
    __syncthreads();
    const float4* W  = (const float4*)(W_fb + (size_t)lane*128);   // l = 0
    const float4* c4 = (const float4*)comb4[wid];
    float g0=0.f,g1=0.f;
    #pragma unroll
    for (int k=0;k<32;k+=2){
      float4 w0=W[k],   c0=c4[k];
      float4 w1=W[k+1], c1=c4[k+1];
      g0 += w0.x*c0.x + w0.y*c0.y + w0.z*c0.z + w0.w*c0.w;
      g1 += w1.x*c1.x + w1.y*c1.y + w1.z*c1.z + w1.w*c1.w;
    }
    float g = sigmoidf_(g0+g1 + b_fb[lane]);
    float xg = xv*g + pvv*(1.0f-g);
    xA[(size_t)row*Dn+lane] = xg;
    xhA[(size_t)row*Dn+lane] = (half_t)xg;
    pnorm_w(xg, row>>9, row&511, row, lane, sA, sThA);
  } else {
    if (tid < 128){
      int b = tid >> 6, d = tid & 63;
      float acc=0.f;
      const float* xb = st3 + (size_t)b*Tn*Dn + d;
      for (int t=0;t<Tn;t++) acc += xb[(size_t)t*Dn];
      pooled[tid] = acc * (1.0f/Tn);
    }
    __syncthreads();
    if (tid < 64){
      int b = tid >> 5, h = tid & 31;
      float acc=0.f;
      #pragma unroll 8
      for (int d2=0; d2<64; d2++) acc += pooled[b*64+d2]*Wc1[h*64+d2];
      h1[tid] = tanhf(acc + bc1[h]);
    }
    __syncthreads();
    if (tid < 128){
      int b = tid >> 6, d = tid & 63;
      float acc=0.f;
      #pragma unroll 8
      for (int h2=0; h2<32; h2++) acc += h1[b*32+h2]*Wc2[d*32+h2];
      hb[tid] = tanhf(acc + bc2[d]);
    }
    __syncthreads();
    if (tid < 64){
      float agg = 0.5f*(hb[tid] + hb[64+tid]);
      combb[tid] = cb_in[tid];
      combb[64+tid] = agg;
    }
    __syncthreads();
    if (tid < 64){
      float acc=0.f;
      #pragma unroll 8
      for (int k=0;k<128;k++) acc += Wu[tid*128+k]*combb[k];
      float g = sigmoidf_(acc + bu[tid]);
      float nb = combb[tid]*(1.0f-g) + combb[64+tid]*g;
      cb_out[tid] = nb;
      #pragma unroll
      for (int l=0;l<4;l++){
        float v = wrs(W_temp[l*Dn + tid]*nb);
        if (tid==0) temps[l] = sigmoidf_(v + b_temp[l]) + 0.5f;
      }
    }
  }
}

extern "C" void kernel_launch(void* const* d_in, const int* in_sizes, int n_in,
                              void* d_out, int out_size, void* d_ws, size_t ws_size,
                              hipStream_t stream) {
  const float* basin_seq    = (const float*)d_in[0];
  const float* basin_coords = (const float*)d_in[1];
  const float* W_temp       = (const float*)d_in[2];
  const float* b_temp       = (const float*)d_in[3];
  const float* res_scale    = (const float*)d_in[4];
  const float* W_fb         = (const float*)d_in[5];
  const float* b_fb         = (const float*)d_in[6];
  const float* Wc1          = (const float*)d_in[7];
  const float* bc1          = (const float*)d_in[8];
  const float* Wc2          = (const float*)d_in[9];
  const float* bc2          = (const float*)d_in[10];
  const float* Wu           = (const float*)d_in[11];
  const float* bu           = (const float*)d_in[12];
  const float* rsg          = (const float*)d_in[13];
  float* out = (float*)d_out;
  float* ws  = (float*)d_ws;

  const size_t N = NELEM; // 65536
  float* sA    = ws;
  float* sB    = ws + N;
  float* st    = ws + 2*N;          // st0..st3 : 4*N
  float* xA    = ws + 6*N;
  float* xB    = ws + 7*N;
  half_t* sThA = (half_t*)(ws + 8*N);
  half_t* sThB = (half_t*)(ws + 8*N + N/2);
  half_t* xhBS = (half_t*)(ws + 9*N);
  half_t* xhA  = (half_t*)(ws + 9*N + N/2);
  half_t* xhB  = (half_t*)(ws + 10*N);
  float* temps = ws + 10*N + N/2;
  float* cb    = ws + 10*N + N/2 + 64;
  float* st0 = st, *st1 = st+N, *st2 = st+2*N, *st3 = st+3*N;

  const int GA = 512;  // NI=2 rows/block

  // ---- pass 0
  k_prologue<<<257,256,0,stream>>>(basin_seq, sA, sThA, xhBS, W_temp, b_temp, basin_coords, temps);
  k_attn<0><<<GA,512,0,stream>>>(basin_seq, xhBS, sA, sThA, temps, res_scale, 0,
                                 st0, xhA, sB, sThB, nullptr,nullptr,nullptr,nullptr,nullptr);
  k_attn<0><<<GA,512,0,stream>>>(st0, xhA, sB, sThB, temps, res_scale, 1,
                                 st1, xhB, sA, sThA, nullptr,nullptr,nullptr,nullptr,nullptr);
  k_attn<0><<<GA,512,0,stream>>>(st1, xhB, sA, sThA, temps, res_scale, 2,
                                 st2, xhA, sB, sThB, nullptr,nullptr,nullptr,nullptr,nullptr);
  k_attn<1><<<GA,512,0,stream>>>(st2, xhA, sB, sThB, temps, res_scale, 3,
                                 st3, nullptr, nullptr, nullptr, nullptr,nullptr,nullptr,nullptr,nullptr);
  // ---- basin update + pass-1 layer-0 prep
  k_basinprep<<<257,256,0,stream>>>(st3, st0, W_fb, b_fb, xA, xhA, sA, sThA,
                                    Wc1, bc1, Wc2, bc2, Wu, bu,
                                    basin_coords, cb, W_temp, b_temp, temps);
  // ---- pass 1
  k_attn<2><<<GA,512,0,stream>>>(xA, xhA, sA, sThA, temps, res_scale, 0,
                                 xB, xhB, sB, sThB,
                                 W_fb + (size_t)1*Dn*2*Dn, b_fb + 1*Dn, st1, nullptr,nullptr);
  k_attn<2><<<GA,512,0,stream>>>(xB, xhB, sB, sThB, temps, res_scale, 1,
                                 xA, xhA, sA, sThA,
                                 W_fb + (size_t)2*Dn*2*Dn, b_fb + 2*Dn, st2, nullptr,nullptr);
  k_attn<2><<<GA,512,0,stream>>>(xA, xhA, sA, sThA, temps, res_scale, 2,
                                 xB, xhB, sB, sThB,
                                 W_fb + (size_t)3*Dn*2*Dn, b_fb + 3*Dn, st3, nullptr,nullptr);
  k_attn<3><<<GA,512,0,stream>>>(xB, xhB, sB, sThB, temps, res_scale, 3,
                                 out, nullptr, nullptr, nullptr,
                                 nullptr,nullptr,nullptr, basin_seq, rsg);
}